// Round 6
// baseline (31.616 us; speedup 1.0000x reference)
//
#include <hip/hip_runtime.h>

#define NS 384
#define NT 384
#define D  256
#define NTILE 24              // 16-row tiles
#define RN_STRIDE 408         // LDS Rn stride: 816B = 51*16 (aligned frags, ~2-way banks)
#define FXP 1048576.0         // 2^20 fixed point

typedef __attribute__((ext_vector_type(8))) short bf16x8;
typedef __attribute__((ext_vector_type(4))) float f32x4;

__device__ __forceinline__ unsigned short f2bf(float f) {   // RNE f32 -> bf16
    unsigned u = __float_as_uint(f);
    return (unsigned short)((u + 0x7FFFu + ((u >> 16) & 1u)) >> 16);
}
__device__ __forceinline__ float bf2f(unsigned short h) {
    return __uint_as_float(((unsigned)h) << 16);
}

// Node 1: 48 blocks. Blocks 0..23: src tile j -> src_bf, srcT (pair-packed),
// ns2 (f32 exact), masked block-diag Gram via MFMA -> Hg bf16 (k-padded 0).
// Blocks 24..47: trgt tile -> trgt_bf, nt2. Block 0 resets llsum/cnt.
__global__ __launch_bounds__(256) void k_prep(
        const float* __restrict__ src, const float* __restrict__ trgt,
        unsigned short* __restrict__ src_bf, unsigned short* __restrict__ trgt_bf,
        unsigned short* __restrict__ srcT, unsigned short* __restrict__ Hg,
        float* __restrict__ ns2, float* __restrict__ nt2,
        unsigned long long* __restrict__ llsum, unsigned* __restrict__ cnt) {
    const int b = blockIdx.x, tid = threadIdx.x;
    if (b == 0 && tid == 0) { *llsum = 0ull; *cnt = 0u; }
    const bool isSrc = (b < NTILE);
    const int j = isSrc ? b : b - NTILE;
    const float* inp = isSrc ? src : trgt;
    unsigned short* outbf = isSrc ? src_bf : trgt_bf;

    __shared__ unsigned short Sb[16][272];   // bf16 tile for Gram frags
    __shared__ float red[16][32];

    const int p    = tid >> 5;        // row pair 0..7
    const int dseg = tid & 31;        // 8-dim segment
    const int d0   = dseg * 8;
    const int r0   = 2 * p, r1 = r0 + 1;
    const int gi0  = 16 * j + r0, gi1 = gi0 + 1;

    const float4 a0 = *(const float4*)&inp[gi0 * D + d0];
    const float4 a1 = *(const float4*)&inp[gi0 * D + d0 + 4];
    const float4 c0 = *(const float4*)&inp[gi1 * D + d0];
    const float4 c1 = *(const float4*)&inp[gi1 * D + d0 + 4];

    unsigned short sa[8] = {f2bf(a0.x), f2bf(a0.y), f2bf(a0.z), f2bf(a0.w),
                            f2bf(a1.x), f2bf(a1.y), f2bf(a1.z), f2bf(a1.w)};
    unsigned short sc[8] = {f2bf(c0.x), f2bf(c0.y), f2bf(c0.z), f2bf(c0.w),
                            f2bf(c1.x), f2bf(c1.y), f2bf(c1.z), f2bf(c1.w)};

    *(ushort4*)&outbf[gi0 * D + d0]     = make_ushort4(sa[0], sa[1], sa[2], sa[3]);
    *(ushort4*)&outbf[gi0 * D + d0 + 4] = make_ushort4(sa[4], sa[5], sa[6], sa[7]);
    *(ushort4*)&outbf[gi1 * D + d0]     = make_ushort4(sc[0], sc[1], sc[2], sc[3]);
    *(ushort4*)&outbf[gi1 * D + d0 + 4] = make_ushort4(sc[4], sc[5], sc[6], sc[7]);

    if (isSrc) {
        // transposed copy, 2 consecutive i's packed per u32 (i0 = 16j+2p even)
#pragma unroll
        for (int dd = 0; dd < 8; ++dd) {
            const unsigned v = (unsigned)sa[dd] | ((unsigned)sc[dd] << 16);
            *(unsigned*)&srcT[(d0 + dd) * NS + 16 * j + r0] = v;
        }
        *(ushort4*)&Sb[r0][d0]     = make_ushort4(sa[0], sa[1], sa[2], sa[3]);
        *(ushort4*)&Sb[r0][d0 + 4] = make_ushort4(sa[4], sa[5], sa[6], sa[7]);
        *(ushort4*)&Sb[r1][d0]     = make_ushort4(sc[0], sc[1], sc[2], sc[3]);
        *(ushort4*)&Sb[r1][d0 + 4] = make_ushort4(sc[4], sc[5], sc[6], sc[7]);
    }

    red[r0][dseg] = a0.x*a0.x + a0.y*a0.y + a0.z*a0.z + a0.w*a0.w
                  + a1.x*a1.x + a1.y*a1.y + a1.z*a1.z + a1.w*a1.w;
    red[r1][dseg] = c0.x*c0.x + c0.y*c0.y + c0.z*c0.z + c0.w*c0.w
                  + c1.x*c1.x + c1.y*c1.y + c1.z*c1.z + c1.w*c1.w;
    __syncthreads();

    if (tid < 16) {
        float s = 0.f;
#pragma unroll
        for (int k = 0; k < 32; ++k) s += red[tid][k];
        (isSrc ? ns2 : nt2)[16 * j + tid] = s;   // exact f32 row norms
    }

    if (isSrc) {
        if (tid < 64) {   // wave 0: 16x16 Gram via MFMA (A-frag == B-frag)
            const int l = tid;
            f32x4 g = {0.f, 0.f, 0.f, 0.f};
#pragma unroll
            for (int kk = 0; kk < 8; ++kk) {
                const bf16x8 af = *(const bf16x8*)&Sb[l & 15][kk * 32 + (l >> 4) * 8];
                g = __builtin_amdgcn_mfma_f32_16x16x32_bf16(af, af, g, 0, 0, 0);
            }
#pragma unroll
            for (int r = 0; r < 4; ++r) {
                const int rowG = (l >> 4) * 4 + r, colG = l & 15;
                const unsigned short h =
                    ((rowG >> 2) == (colG >> 2)) ? f2bf(g[r]) : (unsigned short)0;
                Hg[(j * 16 + rowG) * 32 + colG] = h;
            }
        }
        Hg[(j * 16 + (tid >> 4)) * 32 + 16 + (tid & 15)] = 0;   // k-pad zeros
    }
}

// Node 2: 24 blocks, one per 16 t-rows. dot GEMM -> rn -> {At, R/P group
// terms, Rn in LDS} -> quad MFMA (Rn*H) -> W GEMM (K=384) -> loss epilogue
// -> fixed-point atomic + counter-gated scalar write.
__global__ __launch_bounds__(256) void k_main(
        const float* __restrict__ trgt,
        const unsigned short* __restrict__ src_bf,
        const unsigned short* __restrict__ trgt_bf,
        const unsigned short* __restrict__ srcT,
        const unsigned short* __restrict__ Hg,
        const float* __restrict__ ns2, const float* __restrict__ nt2,
        unsigned long long* __restrict__ llsum, unsigned* __restrict__ cnt,
        float* __restrict__ out) {
    const int b = blockIdx.x, tid = threadIdx.x;
    const int w = tid >> 6, l = tid & 63;
    const int T0 = b * 16;
    const int lc = l & 15, lr4 = l >> 4;

    __shared__ unsigned short Rn[16][RN_STRIDE];
    __shared__ float AtP[4][16], GrpP[4][16], LossP[4][16];
    __shared__ float nt2s[16], Ats[16], Grps[16];

    for (int idx = tid; idx < 16 * RN_STRIDE / 2; idx += 256)
        ((unsigned*)&Rn[0][0])[idx] = 0u;               // zero (tail cols matter)
    if (tid < 16) nt2s[tid] = nt2[T0 + tid];
    __syncthreads();

    bf16x8 afT[8];
#pragma unroll
    for (int kk = 0; kk < 8; ++kk)
        afT[kk] = *(const bf16x8*)&trgt_bf[(T0 + lc) * D + kk * 32 + lr4 * 8];

    float rnsave[6][4];
    float atp[4] = {0.f, 0.f, 0.f, 0.f};
    float gq[4]  = {0.f, 0.f, 0.f, 0.f};

#pragma unroll
    for (int m = 0; m < 6; ++m) {                       // wave's i-tiles
        const int j = w + 4 * m;
        f32x4 acc = {0.f, 0.f, 0.f, 0.f};
#pragma unroll
        for (int kk = 0; kk < 8; ++kk) {
            const bf16x8 bf = *(const bf16x8*)&src_bf[(16 * j + lc) * D + kk * 32 + lr4 * 8];
            acc = __builtin_amdgcn_mfma_f32_16x16x32_bf16(afT[kk], bf, acc, 0, 0, 0);
        }
        const float ns2v = ns2[16 * j + lc];
#pragma unroll
        for (int r = 0; r < 4; ++r) {
            const int ri = lr4 * 4 + r;
            const float n2 = nt2s[ri] + ns2v - 2.f * acc[r];   // norms ~22, EPS never binds
            const unsigned short rb = f2bf(rsqrtf(n2));
            const float rnf = bf2f(rb);                 // rounded rn == W operand
            rnsave[m][r] = rnf;
            atp[r] += rnf;
            Rn[ri][16 * j + lc] = rb;
            float x = rnf, y = rnf * acc[r];            // R, P over group of 4 cols
            x += __shfl_xor(x, 1, 64); x += __shfl_xor(x, 2, 64);
            y += __shfl_xor(y, 1, 64); y += __shfl_xor(y, 2, 64);
            if ((l & 3) == 0) gq[r] += nt2s[ri] * x * x - 2.f * x * y;
        }
    }
    __syncthreads();                                    // Rn complete

#pragma unroll
    for (int m = 0; m < 6; ++m) {                       // quad: rn . (Rn*H)
        const int j = w + 4 * m;
        const bf16x8 aR = *(const bf16x8*)&Rn[lc][16 * j + lr4 * 8];
        const bf16x8 bH = *(const bf16x8*)&Hg[(j * 16 + lc) * 32 + lr4 * 8];
        f32x4 q = {0.f, 0.f, 0.f, 0.f};
        q = __builtin_amdgcn_mfma_f32_16x16x32_bf16(aR, bH, q, 0, 0, 0);
#pragma unroll
        for (int r = 0; r < 4; ++r) gq[r] += rnsave[m][r] * q[r];
    }

#pragma unroll
    for (int r = 0; r < 4; ++r) {                       // col-sum 16 lanes
        float v = atp[r], u = gq[r];
        v += __shfl_xor(v, 1, 64); v += __shfl_xor(v, 2, 64);
        v += __shfl_xor(v, 4, 64); v += __shfl_xor(v, 8, 64);
        u += __shfl_xor(u, 1, 64); u += __shfl_xor(u, 2, 64);
        u += __shfl_xor(u, 4, 64); u += __shfl_xor(u, 8, 64);
        if ((l & 15) == 0) { AtP[w][lr4 * 4 + r] = v; GrpP[w][lr4 * 4 + r] = u; }
    }
    __syncthreads();
    if (tid < 16) {
        Ats[tid]  = AtP[0][tid] + AtP[1][tid] + AtP[2][tid] + AtP[3][tid];
        Grps[tid] = GrpP[0][tid] + GrpP[1][tid] + GrpP[2][tid] + GrpP[3][tid];
    }

    bf16x8 afW[12];
#pragma unroll
    for (int kk = 0; kk < 12; ++kk)
        afW[kk] = *(const bf16x8*)&Rn[lc][kk * 32 + lr4 * 8];

    f32x4 wacc[4];
#pragma unroll
    for (int md = 0; md < 4; ++md) {                    // W GEMM: 4 d-tiles/wave
        const int jd = 4 * w + md;
        f32x4 acc = {0.f, 0.f, 0.f, 0.f};
#pragma unroll
        for (int kk = 0; kk < 12; ++kk) {
            const bf16x8 bf = *(const bf16x8*)&srcT[(16 * jd + lc) * NS + kk * 32 + lr4 * 8];
            acc = __builtin_amdgcn_mfma_f32_16x16x32_bf16(afW[kk], bf, acc, 0, 0, 0);
        }
        wacc[md] = acc;
    }
    __syncthreads();                                    // Ats/Grps visible

    float lacc[4] = {0.f, 0.f, 0.f, 0.f};
#pragma unroll
    for (int md = 0; md < 4; ++md) {
        const int jd = 4 * w + md;
#pragma unroll
        for (int r = 0; r < 4; ++r) {
            const int ri = lr4 * 4 + r;
            const float tf = trgt[(T0 + ri) * D + 16 * jd + lc];   // f32 exact
            const float s = Ats[ri] * tf - wacc[md][r];
            lacc[r] += s * s;
        }
    }
#pragma unroll
    for (int r = 0; r < 4; ++r) {
        float v = lacc[r];
        v += __shfl_xor(v, 1, 64); v += __shfl_xor(v, 2, 64);
        v += __shfl_xor(v, 4, 64); v += __shfl_xor(v, 8, 64);
        if ((l & 15) == 0) LossP[w][lr4 * 4 + r] = v;
    }
    __syncthreads();

    if (tid == 0) {
        double tot = 0.0;
#pragma unroll
        for (int t = 0; t < 16; ++t) {
            const float ss = LossP[0][t] + LossP[1][t] + LossP[2][t] + LossP[3][t];
            tot += (double)(ss - 2.f * Grps[t]);
        }
        const long long ll = llrint(tot * FXP);
        atomicAdd(llsum, (unsigned long long)ll);
        __threadfence();
        const unsigned old = atomicAdd(cnt, 1u);
        if (old == NTILE - 1) {
            const unsigned long long sv = atomicAdd(llsum, 0ull);
            const double total = (double)(long long)sv / FXP;
            out[0] = (float)(total / ((double)NS * (double)NS * (double)NT));
        }
    }
}

extern "C" void kernel_launch(void* const* d_in, const int* in_sizes, int n_in,
                              void* d_out, int out_size, void* d_ws, size_t ws_size,
                              hipStream_t stream) {
    const float* src  = (const float*)d_in[0];   // [384,256] f32
    const float* trgt = (const float*)d_in[1];   // [384,256] f32

    char* ws = (char*)d_ws;
    float* ns2 = (float*)ws;                               // [384]
    float* nt2 = ns2 + NS;                                 // [384]
    unsigned long long* llsum = (unsigned long long*)(nt2 + NT);   // 8B aligned
    unsigned* cnt = (unsigned*)(llsum + 1);
    unsigned short* src_bf  = (unsigned short*)(llsum + 2);        // 16B aligned
    unsigned short* trgt_bf = src_bf + (size_t)NS * D;
    unsigned short* srcT    = trgt_bf + (size_t)NT * D;            // [256][384]
    unsigned short* Hg      = srcT + (size_t)D * NS;               // [24][16][32]
    float* out = (float*)d_out;

    k_prep<<<2 * NTILE, 256, 0, stream>>>(src, trgt, src_bf, trgt_bf, srcT, Hg,
                                          ns2, nt2, llsum, cnt);
    k_main<<<NTILE, 256, 0, stream>>>(trgt, src_bf, trgt_bf, srcT, Hg,
                                      ns2, nt2, llsum, cnt, out);
}

// Round 7
// 20.976 us; speedup vs baseline: 1.5072x; 1.5072x over previous
//
#include <hip/hip_runtime.h>

#define NS 384
#define NT 384
#define D  256
#define NTILE 24          // 16-row t-tiles
#define NSUB  24          // 6 i-slices * 4 waves = per-tile subtile count
#define FXP 1048576.0     // 2^20 fixed point

typedef __attribute__((ext_vector_type(8))) short bf16x8;
typedef __attribute__((ext_vector_type(4))) float f32x4;

__device__ __forceinline__ unsigned short f2bf(float f) {   // RNE f32 -> bf16
    unsigned u = __float_as_uint(f);
    return (unsigned short)((u + 0x7FFFu + ((u >> 16) & 1u)) >> 16);
}
__device__ __forceinline__ float bf2f(unsigned short h) {
    return __uint_as_float(((unsigned)h) << 16);
}
// 8 consecutive f32 -> bf16x8 frag; accumulates sum of squares of ROUNDED values
__device__ __forceinline__ bf16x8 load8_bf(const float* __restrict__ p, float& ss) {
    const float4 f0 = *(const float4*)p;
    const float4 f1 = *(const float4*)(p + 4);
    const float vf[8] = {f0.x, f0.y, f0.z, f0.w, f1.x, f1.y, f1.z, f1.w};
    bf16x8 r;
#pragma unroll
    for (int j = 0; j < 8; ++j) {
        const unsigned short h = f2bf(vf[j]);
        r[j] = (short)h;
        const float v = bf2f(h);
        ss += v * v;
    }
    return r;
}

// Node A: 144 blocks = (t-tile 0..23) x (i-slice 0..5). Wave = one 16x16
// (t,i) tile. In-register bf16 cast; Gram MFMA -> group quad terms; dot
// MFMA -> rn -> rnb bf16 + At/grp subtile partials. tile==0 blocks emit srcT.
__global__ __launch_bounds__(256) void k_a(
        const float* __restrict__ src, const float* __restrict__ trgt,
        unsigned short* __restrict__ rnb, unsigned short* __restrict__ srcT,
        float* __restrict__ AtPart, float* __restrict__ GrpPart,
        unsigned long long* __restrict__ llsum, unsigned* __restrict__ cnt) {
    const int b    = blockIdx.x;
    const int tile = b % NTILE;
    const int sl   = b / NTILE;
    const int tid  = threadIdx.x;
    const int w = tid >> 6, l = tid & 63;
    const int lc = l & 15, lr4 = l >> 4;
    if (b == 0 && tid == 0) { *llsum = 0ull; *cnt = 0u; }

    const int T0 = tile * 16;
    const int i0 = sl * 64 + w * 16;

    // target A-frags + ||t_row||^2 partial (lr4 dim-slice), reduced via 2 shfl
    bf16x8 at[8]; float nt2p = 0.f;
#pragma unroll
    for (int kk = 0; kk < 8; ++kk)
        at[kk] = load8_bf(&trgt[(T0 + lc) * D + kk * 32 + lr4 * 8], nt2p);
    nt2p += __shfl_xor(nt2p, 16, 64);
    nt2p += __shfl_xor(nt2p, 32, 64);    // all lanes: nt2 of t-row lc

    // src B-frags + ||s_i||^2
    bf16x8 as_[8]; float ns2p = 0.f;
#pragma unroll
    for (int kk = 0; kk < 8; ++kk)
        as_[kk] = load8_bf(&src[(i0 + lc) * D + kk * 32 + lr4 * 8], ns2p);
    ns2p += __shfl_xor(ns2p, 16, 64);
    ns2p += __shfl_xor(ns2p, 32, 64);    // all lanes: ns2 of src-row lc

    // local 16x16 Gram (A == B); diag-holder lanes publish their group column
    f32x4 g = {0.f, 0.f, 0.f, 0.f};
#pragma unroll
    for (int kk = 0; kk < 8; ++kk)
        g = __builtin_amdgcn_mfma_f32_16x16x32_bf16(as_[kk], as_[kk], g, 0, 0, 0);
    __shared__ float4 Glds[4][16];       // wave-private: Glds[w][a] = G[grp(a)][a]
    if (lr4 == (lc >> 2))
        Glds[w][lc] = make_float4(g[0], g[1], g[2], g[3]);

    // dot GEMM: dot[t-row][i-col]
    f32x4 acc = {0.f, 0.f, 0.f, 0.f};
#pragma unroll
    for (int kk = 0; kk < 8; ++kk)
        acc = __builtin_amdgcn_mfma_f32_16x16x32_bf16(at[kk], as_[kk], acc, 0, 0, 0);
    __syncthreads();                     // Glds visible (also cross-wave safe)

    const float4 gl = Glds[w][lc];       // {G[gb+0][lc] .. G[gb+3][lc]}, symmetric
    const int lbase = (l & 48) | (lc & 12);

    float atrow[4], grprow[4];
#pragma unroll
    for (int r = 0; r < 4; ++r) {
        const int ri   = lr4 * 4 + r;
        const float dotv = acc[r];
        const float nt2v = __shfl(nt2p, ri, 64);
        const float n2   = nt2v + ns2p - 2.f * dotv;   // norms ~22, EPS never binds
        const unsigned short rbits = f2bf(rsqrtf(n2));
        const float rnf  = bf2f(rbits);                // rounded rn == W operand
        // j-ordered rn of the 4 group members
        const float rn0 = __shfl(rnf, lbase | 0, 64);
        const float rn1 = __shfl(rnf, lbase | 1, 64);
        const float rn2 = __shfl(rnf, lbase | 2, 64);
        const float rn3 = __shfl(rnf, lbase | 3, 64);
        const float R = rn0 + rn1 + rn2 + rn3;
        const float z = gl.x * rn0 + gl.y * rn1 + gl.z * rn2 + gl.w * rn3;
        float pv = rnf * dotv;                         // P = sum rn*dot over group
        pv += __shfl_xor(pv, 1, 64); pv += __shfl_xor(pv, 2, 64);
        float qv = rnf * z;                            // quad = rn^T G rn
        qv += __shfl_xor(qv, 1, 64); qv += __shfl_xor(qv, 2, 64);
        float gval = nt2v * R * R - 2.f * R * pv + qv; // ||S_g||^2
        gval += __shfl_xor(gval, 4, 64);
        gval += __shfl_xor(gval, 8, 64);               // sum the wave's 4 groups
        grprow[r] = gval;
        float av = rnf;                                // At partial over 16 cols
        av += __shfl_xor(av, 1, 64); av += __shfl_xor(av, 2, 64);
        av += __shfl_xor(av, 4, 64); av += __shfl_xor(av, 8, 64);
        atrow[r] = av;
        rnb[(T0 + ri) * NS + i0 + lc] = rbits;
    }

    const int sub = sl * 4 + w;
    if (lc == 0) {
#pragma unroll
        for (int r = 0; r < 4; ++r) {
            AtPart [(tile * NSUB + sub) * 16 + lr4 * 4 + r] = atrow[r];
            GrpPart[(tile * NSUB + sub) * 16 + lr4 * 4 + r] = grprow[r];
        }
    }

    if (tile == 0) {                     // 6 blocks cover all i; emit srcT[d][i]
#pragma unroll
        for (int kk = 0; kk < 8; ++kk)
#pragma unroll
            for (int j = 0; j < 8; ++j) {
                const int d = kk * 32 + lr4 * 8 + j;
                srcT[d * NS + i0 + lc] = (unsigned short)as_[kk][j];
            }
    }
}

// Node B: 96 blocks = (t-tile) x (d-slice of 64). W-GEMM K=384 from
// rnb/srcT; loss epilogue vs f32 trgt; fixed-point atomic + gated write.
__global__ __launch_bounds__(256) void k_b(
        const float* __restrict__ trgt,
        const unsigned short* __restrict__ rnb,
        const unsigned short* __restrict__ srcT,
        const float* __restrict__ AtPart, const float* __restrict__ GrpPart,
        unsigned long long* __restrict__ llsum, unsigned* __restrict__ cnt,
        float* __restrict__ out) {
    const int b = blockIdx.x;
    const int tile = b >> 2, ds = b & 3;
    const int tid = threadIdx.x, w = tid >> 6, l = tid & 63;
    const int lc = l & 15, lr4 = l >> 4;
    const int T0 = tile * 16;
    const int c0 = ds * 64 + w * 16;     // wave's d-col base

    __shared__ float At16[16], Grp16[16], LossP[4][16];
    if (tid < 16) {
        float s = 0.f;
#pragma unroll
        for (int q = 0; q < NSUB; ++q) s += AtPart[(tile * NSUB + q) * 16 + tid];
        At16[tid] = s;
    } else if (tid < 32) {
        const int rr = tid - 16;
        float s = 0.f;
#pragma unroll
        for (int q = 0; q < NSUB; ++q) s += GrpPart[(tile * NSUB + q) * 16 + rr];
        Grp16[rr] = s;
    }

    f32x4 acc = {0.f, 0.f, 0.f, 0.f};
#pragma unroll
    for (int kk = 0; kk < 12; ++kk) {
        const bf16x8 af = *(const bf16x8*)&rnb [(T0 + lc) * NS + kk * 32 + lr4 * 8];
        const bf16x8 bf = *(const bf16x8*)&srcT[(c0 + lc) * NS + kk * 32 + lr4 * 8];
        acc = __builtin_amdgcn_mfma_f32_16x16x32_bf16(af, bf, acc, 0, 0, 0);
    }
    __syncthreads();                     // At16/Grp16 ready

    float lacc[4];
#pragma unroll
    for (int r = 0; r < 4; ++r) {
        const int ri = lr4 * 4 + r;
        const float tf = trgt[(T0 + ri) * D + c0 + lc];   // f32 exact
        const float S  = At16[ri] * tf - acc[r];
        float v = S * S;
        v += __shfl_xor(v, 1, 64); v += __shfl_xor(v, 2, 64);
        v += __shfl_xor(v, 4, 64); v += __shfl_xor(v, 8, 64);
        lacc[r] = v;                     // row partial over this wave's 16 cols
    }
    if (lc == 0) {
#pragma unroll
        for (int r = 0; r < 4; ++r) LossP[w][lr4 * 4 + r] = lacc[r];
    }
    __syncthreads();

    if (tid == 0) {
        double tot = 0.0;
#pragma unroll
        for (int t = 0; t < 16; ++t)
            tot += (double)(LossP[0][t] + LossP[1][t] + LossP[2][t] + LossP[3][t]);
        if (ds == 0) {
            float gg = 0.f;
#pragma unroll
            for (int t = 0; t < 16; ++t) gg += Grp16[t];
            tot -= 2.0 * (double)gg;
        }
        const long long ll = llrint(tot * FXP);
        atomicAdd(llsum, (unsigned long long)ll);
        __threadfence();
        const unsigned old = atomicAdd(cnt, 1u);
        if (old == 96 - 1) {
            const unsigned long long sv = atomicAdd(llsum, 0ull);
            const double total = (double)(long long)sv / FXP;
            out[0] = (float)(total / ((double)NS * (double)NS * (double)NT));
        }
    }
}

extern "C" void kernel_launch(void* const* d_in, const int* in_sizes, int n_in,
                              void* d_out, int out_size, void* d_ws, size_t ws_size,
                              hipStream_t stream) {
    const float* src  = (const float*)d_in[0];   // [384,256] f32
    const float* trgt = (const float*)d_in[1];   // [384,256] f32

    unsigned long long* llsum = (unsigned long long*)d_ws;
    unsigned* cnt = (unsigned*)(llsum + 1);
    unsigned short* rnb  = (unsigned short*)((char*)d_ws + 16);   // [384][384]
    unsigned short* srcT = rnb + (size_t)NT * NS;                 // [256][384]
    float* AtPart  = (float*)(srcT + (size_t)D * NS);             // [24][24][16]
    float* GrpPart = AtPart + NTILE * NSUB * 16;                  // [24][24][16]
    float* out = (float*)d_out;

    k_a<<<NTILE * 6, 256, 0, stream>>>(src, trgt, rnb, srcT, AtPart, GrpPart,
                                       llsum, cnt);
    k_b<<<NTILE * 4, 256, 0, stream>>>(trgt, rnb, srcT, AtPart, GrpPart,
                                       llsum, cnt, out);
}